// Round 5
// baseline (453.244 us; speedup 1.0000x reference)
//
#include <hip/hip_runtime.h>
#include <math.h>

#define NUM_CLASSES 81
#define BATCH 64
#define P 8732
#define M 24
#define THRESH 0.5f
#define R_TOTAL (BATCH * P)          // 558848
#define RPB 64                       // rows per block in stream kernel
#define LDS_PITCH 85                 // padded row pitch (dwords)
#define NBLK_A 35                    // ceil(P/256)

__device__ __forceinline__ float sl1f(float d) {
    float a = fabsf(d);
    return a < 1.f ? 0.5f * a * a : a - 0.5f;
}

__device__ __forceinline__ unsigned long long packkey(float v, int p) {
    return ((unsigned long long)__float_as_uint(v) << 32)
         | (unsigned long long)(0xFFFFFFFFu - (unsigned)p);
}

// ---------- Kernel A: per-prior match; per-truth best via guarded LDS atomicMax ----------
__global__ __launch_bounds__(256) void prior_match_kernel(
    const float* __restrict__ priors,   // [P,4] center-size
    const float* __restrict__ truths,   // [B,M,4] corners
    const int*   __restrict__ labels,   // [B,M]
    unsigned short* __restrict__ cmb,   // [B,P] conf | (bti<<8)
    unsigned long long* __restrict__ bpk_part) // [B,NBLK_A,M] per-block partial best
{
    const int b   = blockIdx.y;
    const int tid = threadIdx.x;
    const int p   = blockIdx.x * 256 + tid;

    __shared__ float s_truth[M][4];
    __shared__ float s_area[M];
    __shared__ int   s_label[M];
    __shared__ unsigned long long s_bk[M];

    if (tid < M * 4) ((float*)s_truth)[tid] = truths[b * M * 4 + tid];
    if (tid < M)     { s_label[tid] = labels[b * M + tid]; s_bk[tid] = 0ull; }
    __syncthreads();
    if (tid < M)
        s_area[tid] = (s_truth[tid][2] - s_truth[tid][0]) * (s_truth[tid][3] - s_truth[tid][1]);
    __syncthreads();

    if (p < P) {
        float4 pr = ((const float4*)priors)[p];
        float bx0 = pr.x - pr.z * 0.5f, by0 = pr.y - pr.w * 0.5f;
        float bx1 = pr.x + pr.z * 0.5f, by1 = pr.y + pr.w * 0.5f;
        float area_b = (bx1 - bx0) * (by1 - by0);

        float best = -1.f; int besti = 0;
#pragma unroll
        for (int m = 0; m < M; ++m) {
            float lx = fmaxf(s_truth[m][0], bx0);
            float ly = fmaxf(s_truth[m][1], by0);
            float rx = fminf(s_truth[m][2], bx1);
            float ry = fminf(s_truth[m][3], by1);
            float w = fmaxf(rx - lx, 0.f), h = fmaxf(ry - ly, 0.f);
            float inter = w * h;
            float iou = inter / (s_area[m] + area_b - inter);
            if (iou > best) { best = iou; besti = m; }        // first m wins ties
            unsigned long long key = packkey(iou, p);         // tie -> smaller p
            if (key > s_bk[m]) atomicMax(&s_bk[m], key);      // guarded; races benign
        }
        int conf = (best < THRESH) ? 0 : (s_label[besti] + 1);
        cmb[(size_t)b * P + p] = (unsigned short)(conf | (besti << 8));
    }
    __syncthreads();
    if (tid < M)
        bpk_part[((size_t)b * NBLK_A + blockIdx.x) * M + tid] = s_bk[tid];
}

// ---------- Kernel B: merge partials, forced matches, zero accumulators ----------
__global__ __launch_bounds__(64) void force_match_kernel(
    const unsigned long long* __restrict__ bpk_part,
    const int* __restrict__ labels,
    unsigned short* __restrict__ cmb,
    double* __restrict__ loss_l,
    double* __restrict__ pos_ce,
    int*    __restrict__ num_pos)
{
    const int b   = blockIdx.x;
    const int tid = threadIdx.x;
    unsigned int pm = 0xFFFFFFFFu;
    if (tid < M) {
        unsigned long long best = 0ull;
        const unsigned long long* part = bpk_part + (size_t)b * NBLK_A * M + tid;
        for (int blk = 0; blk < NBLK_A; ++blk) {
            unsigned long long v = part[(size_t)blk * M];
            if (v > best) best = v;
        }
        pm = 0xFFFFFFFFu - (unsigned)(best & 0xFFFFFFFFull);
    }
    bool dead = false;
    for (int m2 = 1; m2 < M; ++m2) {
        unsigned int p2 = __shfl(pm, m2);
        if (tid < m2 && p2 == pm) dead = true;   // a later m claims same prior
    }
    if (tid < M && !dead)
        cmb[(size_t)b * P + pm] =
            (unsigned short)((labels[b * M + tid] + 1) | (tid << 8));
    if (tid == 0) {
        loss_l[b] = 0.0;
        pos_ce[b] = 0.0;
        num_pos[b] = 0;
    }
}

// ---------- Kernel C: fused stream logsumexp + CE + loc loss ----------
// block = 256 thr handles 64 rows = 20736 B, block base 16B-aligned.
__global__ __launch_bounds__(256) void stream_fused_kernel(
    const float* __restrict__ conf_data,  // [B*P, 81]
    const float* __restrict__ loc_data,   // [B*P, 4]
    const float* __restrict__ priors,     // [P, 4]
    const float* __restrict__ truths,     // [B, M, 4]
    const unsigned short* __restrict__ cmb,
    float*  __restrict__ loss_rank,       // [B*P] out
    double* __restrict__ loss_l,          // [B] accum (zeroed by force_match)
    double* __restrict__ pos_ce,          // [B]
    int*    __restrict__ num_pos)         // [B]
{
    const int tid = threadIdx.x;
    __shared__ float s[RPB * LDS_PITCH];  // 64*85 dwords = 21760 B

    const size_t gbase = (size_t)blockIdx.x * (RPB * NUM_CLASSES); // dwords
    const float4* src4 = (const float4*)(conf_data + gbase);       // 16B-aligned

    for (int f = tid; f < (RPB * NUM_CLASSES) / 4; f += 256) {
        float4 v = src4[f];
        int d = 4 * f;
#pragma unroll
        for (int j = 0; j < 4; ++j) {
            int dj  = d + j;
            int row = (unsigned)dj / NUM_CLASSES;
            int col = dj - row * NUM_CLASSES;
            s[row * LDS_PITCH + col] = ((const float*)&v)[j];
        }
    }
    __syncthreads();

    const int rq = tid >> 2;        // row 0..63
    const int l  = tid & 3;         // quad lane
    const float* srow = s + rq * LDS_PITCH;
    float a0 = 0.f, a1 = 0.f, a2 = 0.f, a3 = 0.f;
#pragma unroll
    for (int j = 0; j < 20; j += 4) {
        a0 += __expf(srow[l * 20 + j]);
        a1 += __expf(srow[l * 20 + j + 1]);
        a2 += __expf(srow[l * 20 + j + 2]);
        a3 += __expf(srow[l * 20 + j + 3]);
    }
    float sum = (a0 + a1) + (a2 + a3);
    sum += __shfl_xor(sum, 1);
    sum += __shfl_xor(sum, 2);

    const int r = blockIdx.x * RPB + rq;
    float ll = 0.f, ce = 0.f;
    int np = 0, myb = 0;
    if (l == 0) {
        float se  = sum + __expf(srow[80]);
        float lse = __logf(se);
        unsigned cm = cmb[r];
        int conf = cm & 0xFF;
        myb = (unsigned)r / P;
        if (conf > 0) {
            int mt = cm >> 8;
            int p  = r - myb * P;
            ce = lse - srow[conf];
            np = 1;
            loss_rank[r] = 0.f;
            float4 t  = ((const float4*)truths)[myb * M + mt];
            float4 pr = ((const float4*)priors)[p];
            float4 ld = ((const float4*)loc_data)[r];
            float gcx = ((t.x + t.z) * 0.5f - pr.x) / (0.1f * pr.z);
            float gcy = ((t.y + t.w) * 0.5f - pr.y) / (0.1f * pr.w);
            float gw  = logf((t.z - t.x) / pr.z) / 0.2f;
            float gh  = logf((t.w - t.y) / pr.w) / 0.2f;
            ll = sl1f(ld.x - gcx) + sl1f(ld.y - gcy) + sl1f(ld.z - gw) + sl1f(ld.w - gh);
        } else {
            loss_rank[r] = lse - srow[0];
        }
    }

    // sparse accumulation; a block's 64 rows may straddle one batch boundary
    if (__any(np)) {
        const int b0 = (blockIdx.x * RPB) / P;
        float ll0 = (myb == b0) ? ll : 0.f, ll1 = ll - ll0;
        float ce0 = (myb == b0) ? ce : 0.f, ce1 = ce - ce0;
        int   np0 = (myb == b0) ? np : 0,   np1 = np - np0;
#pragma unroll
        for (int off = 32; off; off >>= 1) {
            ll0 += __shfl_xor(ll0, off); ll1 += __shfl_xor(ll1, off);
            ce0 += __shfl_xor(ce0, off); ce1 += __shfl_xor(ce1, off);
            np0 += __shfl_xor(np0, off); np1 += __shfl_xor(np1, off);
        }
        if ((tid & 63) == 0) {
            if (np0 > 0) {
                atomicAdd(&loss_l[b0], (double)ll0);
                atomicAdd(&pos_ce[b0], (double)ce0);
                atomicAdd(&num_pos[b0], np0);
            }
            if (np1 > 0) {
                atomicAdd(&loss_l[b0 + 1], (double)ll1);
                atomicAdd(&pos_ce[b0 + 1], (double)ce1);
                atomicAdd(&num_pos[b0 + 1], np1);
            }
        }
    }
}

// ---------- Kernel D: top-k sum via radix select (parallel bucket scan) ----------
__global__ __launch_bounds__(1024) void topk_kernel(
    const float*  __restrict__ loss_rank, // [B,P] nonneg floats
    const int*    __restrict__ num_pos,   // [B]
    const double* __restrict__ pos_ce,    // [B]
    double*       __restrict__ loss_c)    // [B] out
{
    const int b   = blockIdx.x;
    const int tid = threadIdx.x;
    const int NT  = 1024;
    const int NW  = NT / 64;
    __shared__ unsigned int s_key[P];
    __shared__ unsigned int s_hist[256];
    __shared__ unsigned int s_suf[256];
    __shared__ unsigned int s_wtot[4];
    __shared__ unsigned int s_prefix;
    __shared__ int s_rem;
    __shared__ double s_dl[NW];
    __shared__ int    s_ci[NW];

    const unsigned int* src = (const unsigned int*)(loss_rank + (size_t)b * P);
    for (int p = tid; p < P; p += NT) s_key[p] = src[p];
    int k = num_pos[b] * 3;
    if (k > P - 1) k = P - 1;
    __syncthreads();

    unsigned int prefix = 0;
    if (k > 0) {
        int rem = k;
        for (int byte = 3; byte >= 0; --byte) {
            if (tid < 256) s_hist[tid] = 0;
            __syncthreads();
            unsigned int himask = (byte == 3) ? 0u : (0xFFFFFFFFu << ((byte + 1) * 8));
            for (int p = tid; p < P; p += NT) {
                unsigned int key = s_key[p];
                if ((key & himask) == prefix)
                    atomicAdd(&s_hist[(key >> (byte * 8)) & 255u], 1u);
            }
            __syncthreads();
            // parallel suffix sum over 256 buckets (threads 0..255 = waves 0..3)
            if (tid < 256) {
                unsigned x = s_hist[tid];
#pragma unroll
                for (int off = 1; off < 64; off <<= 1) {
                    unsigned y = __shfl_down(x, off);
                    if ((tid & 63) + off < 64) x += y;
                }
                s_suf[tid] = x;                      // in-wave inclusive suffix
                if ((tid & 63) == 0) s_wtot[tid >> 6] = x;
            }
            __syncthreads();
            if (tid < 256) {
                unsigned above_w = 0;
                int w = tid >> 6;
                for (int w2 = w + 1; w2 < 4; ++w2) above_w += s_wtot[w2];
                unsigned h    = s_hist[tid];
                unsigned incl = s_suf[tid] + above_w;   // keys in buckets >= tid
                unsigned above = incl - h;              // keys in buckets >  tid
                if ((int)above < rem && rem <= (int)incl) {
                    s_prefix = prefix | ((unsigned)tid << (byte * 8));
                    s_rem = rem - (int)above;
                }
            }
            __syncthreads();
            prefix = s_prefix;
            rem    = s_rem;
        }
    }

    double sum_gt = 0.0;
    int    cnt_gt = 0;
    if (k > 0) {
        for (int p = tid; p < P; p += NT) {
            unsigned int key = s_key[p];
            if (key > prefix) { sum_gt += (double)__uint_as_float(key); ++cnt_gt; }
        }
    }
    for (int off = 32; off; off >>= 1) {
        sum_gt += __shfl_xor(sum_gt, off);
        cnt_gt += __shfl_xor(cnt_gt, off);
    }
    const int wid = tid >> 6;
    if ((tid & 63) == 0) { s_dl[wid] = sum_gt; s_ci[wid] = cnt_gt; }
    __syncthreads();
    if (tid == 0) {
        double sg = 0.0; int cg = 0;
        for (int w = 0; w < NW; ++w) { sg += s_dl[w]; cg += s_ci[w]; }
        double tk = 0.0;
        if (k > 0) tk = sg + (double)(k - cg) * (double)__uint_as_float(prefix);
        loss_c[b] = pos_ce[b] + tk;
    }
}

// ---------- Kernel E: final reduction ----------
__global__ void final_kernel(const double* __restrict__ loss_l,
                             const double* __restrict__ loss_c,
                             const int*    __restrict__ num_pos,
                             float* __restrict__ out)
{
    int t = threadIdx.x; // 64 threads
    double ll = loss_l[t];
    double lc = loss_c[t];
    int    n  = num_pos[t];
    for (int off = 32; off; off >>= 1) {
        ll += __shfl_xor(ll, off);
        lc += __shfl_xor(lc, off);
        n  += __shfl_xor(n, off);
    }
    if (t == 0) {
        double N = (double)n;
        out[0] = (float)(ll / N);
        out[1] = (float)(lc / N);
    }
}

extern "C" void kernel_launch(void* const* d_in, const int* in_sizes, int n_in,
                              void* d_out, int out_size, void* d_ws, size_t ws_size,
                              hipStream_t stream)
{
    const float* loc_data  = (const float*)d_in[0];
    const float* conf_data = (const float*)d_in[1];
    const float* priors    = (const float*)d_in[2];
    const float* truths    = (const float*)d_in[3];
    const int*   labels    = (const int*)d_in[4];
    float* out = (float*)d_out;

    char* ws = (char*)d_ws;
    size_t off = 0;
    float* loss_rank = (float*)(ws + off);             off += (size_t)R_TOTAL * 4;
    unsigned short* cmb = (unsigned short*)(ws + off); off += (size_t)R_TOTAL * 2;
    off = (off + 15) & ~(size_t)15;
    unsigned long long* bpk_part = (unsigned long long*)(ws + off);
    off += (size_t)BATCH * NBLK_A * M * 8;
    int*    num_pos = (int*)(ws + off);    off += 64 * sizeof(int);
    double* loss_l  = (double*)(ws + off); off += 64 * sizeof(double);
    double* pos_ce  = (double*)(ws + off); off += 64 * sizeof(double);
    double* loss_c  = (double*)(ws + off); off += 64 * sizeof(double);

    dim3 gA(NBLK_A, BATCH);
    prior_match_kernel<<<gA, 256, 0, stream>>>(priors, truths, labels, cmb, bpk_part);
    force_match_kernel<<<BATCH, 64, 0, stream>>>(bpk_part, labels, cmb,
                                                 loss_l, pos_ce, num_pos);
    stream_fused_kernel<<<R_TOTAL / RPB, 256, 0, stream>>>(conf_data, loc_data, priors,
                                                           truths, cmb, loss_rank,
                                                           loss_l, pos_ce, num_pos);
    topk_kernel<<<BATCH, 1024, 0, stream>>>(loss_rank, num_pos, pos_ce, loss_c);
    final_kernel<<<1, 64, 0, stream>>>(loss_l, loss_c, num_pos, out);
}

// Round 6
// 143.428 us; speedup vs baseline: 3.1601x; 3.1601x over previous
//
#include <hip/hip_runtime.h>
#include <math.h>

#define NUM_CLASSES 81
#define BATCH 64
#define P 8732
#define M 24
#define THRESH 0.5f
#define R_TOTAL (BATCH * P)          // 558848
#define RPB 64                       // rows per block in stream kernel
#define LDS_PITCH 85                 // padded row pitch (dwords)
#define PPB_A 1024                   // priors per block in match kernel
#define NBLK_A 9                     // ceil(P / PPB_A)

__device__ __forceinline__ float sl1f(float d) {
    float a = fabsf(d);
    return a < 1.f ? 0.5f * a * a : a - 0.5f;
}

__device__ __forceinline__ unsigned long long packkey(float v, int p) {
    return ((unsigned long long)__float_as_uint(v) << 32)
         | (unsigned long long)(0xFFFFFFFFu - (unsigned)p);
}

// ---------- Kernel A: per-prior match; per-truth best via wave shuffle reduce ----------
// 4 priors per thread, m-outer / j-inner (8 scalar regs of running state, no M-arrays).
__global__ __launch_bounds__(256) void prior_match_kernel(
    const float* __restrict__ priors,   // [P,4] center-size
    const float* __restrict__ truths,   // [B,M,4] corners
    const int*   __restrict__ labels,   // [B,M]
    unsigned short* __restrict__ cmb,   // [B,P] conf | (bti<<8)
    unsigned long long* __restrict__ bpk_part) // [B,NBLK_A,M] per-block partial best
{
    const int b    = blockIdx.y;
    const int tid  = threadIdx.x;
    const int base = blockIdx.x * PPB_A;
    const int wid  = tid >> 6;

    __shared__ float s_truth[M][4];
    __shared__ float s_area[M];
    __shared__ int   s_label[M];
    __shared__ float s_v[4][M];
    __shared__ int   s_ix[4][M];

    if (tid < M * 4) ((float*)s_truth)[tid] = truths[b * M * 4 + tid];
    if (tid < M)     s_label[tid] = labels[b * M + tid];
    __syncthreads();
    if (tid < M)
        s_area[tid] = (s_truth[tid][2] - s_truth[tid][0]) * (s_truth[tid][3] - s_truth[tid][1]);
    __syncthreads();

    // load this thread's 4 priors, derive corners
    float bx0[4], by0[4], bx1[4], by1[4], ab[4];
    bool  val[4];
#pragma unroll
    for (int j = 0; j < 4; ++j) {
        int p = base + tid + j * 256;
        val[j] = (p < P);
        float4 pr = ((const float4*)priors)[val[j] ? p : 0];
        bx0[j] = pr.x - pr.z * 0.5f; by0[j] = pr.y - pr.w * 0.5f;
        bx1[j] = pr.x + pr.z * 0.5f; by1[j] = pr.y + pr.w * 0.5f;
        ab[j]  = (bx1[j] - bx0[j]) * (by1[j] - by0[j]);
    }
    float bestv[4] = {-1.f, -1.f, -1.f, -1.f};
    int   bestm[4] = {0, 0, 0, 0};

    for (int m = 0; m < M; ++m) {
        const float tx0 = s_truth[m][0], ty0 = s_truth[m][1];
        const float tx1 = s_truth[m][2], ty1 = s_truth[m][3];
        const float ta  = s_area[m];
        float vmax = -1.f; int ixm = 0x7FFFFFFF;
#pragma unroll
        for (int j = 0; j < 4; ++j) {
            float lx = fmaxf(tx0, bx0[j]);
            float ly = fmaxf(ty0, by0[j]);
            float rx = fminf(tx1, bx1[j]);
            float ry = fminf(ty1, by1[j]);
            float w = fmaxf(rx - lx, 0.f), h = fmaxf(ry - ly, 0.f);
            float inter = w * h;
            float iou = inter / (ta + ab[j] - inter);
            if (!val[j]) iou = -1.f;
            if (iou > bestv[j]) { bestv[j] = iou; bestm[j] = m; }   // first m wins ties
            if (iou > vmax) { vmax = iou; ixm = base + tid + j * 256; } // smaller p wins ties
        }
        // wave reduce (max iou, tie -> smaller p)
        float v = vmax; int ix = ixm;
#pragma unroll
        for (int off = 32; off; off >>= 1) {
            float vo = __shfl_xor(v, off);
            int   io = __shfl_xor(ix, off);
            if (vo > v || (vo == v && io < ix)) { v = vo; ix = io; }
        }
        if ((tid & 63) == 0) { s_v[wid][m] = v; s_ix[wid][m] = ix; }
    }
    __syncthreads();
    if (tid < M) {
        float v = s_v[0][tid]; int ix = s_ix[0][tid];
#pragma unroll
        for (int w = 1; w < 4; ++w) {
            float vo = s_v[w][tid]; int io = s_ix[w][tid];
            if (vo > v || (vo == v && io < ix)) { v = vo; ix = io; }
        }
        bpk_part[((size_t)b * NBLK_A + blockIdx.x) * M + tid] =
            (v >= 0.f) ? packkey(v, ix) : 0ull;
    }
#pragma unroll
    for (int j = 0; j < 4; ++j) {
        if (val[j]) {
            int p = base + tid + j * 256;
            int conf = (bestv[j] < THRESH) ? 0 : (s_label[bestm[j]] + 1);
            cmb[(size_t)b * P + p] = (unsigned short)(conf | (bestm[j] << 8));
        }
    }
}

// ---------- Kernel B: merge partials, forced matches, zero accumulators ----------
__global__ __launch_bounds__(64) void force_match_kernel(
    const unsigned long long* __restrict__ bpk_part,
    const int* __restrict__ labels,
    unsigned short* __restrict__ cmb,
    double* __restrict__ loss_l,
    double* __restrict__ pos_ce,
    int*    __restrict__ num_pos)
{
    const int b   = blockIdx.x;
    const int tid = threadIdx.x;
    unsigned int pm = 0xFFFFFFFFu;
    if (tid < M) {
        unsigned long long best = 0ull;
        const unsigned long long* part = bpk_part + (size_t)b * NBLK_A * M + tid;
#pragma unroll
        for (int blk = 0; blk < NBLK_A; ++blk) {
            unsigned long long v = part[(size_t)blk * M];
            if (v > best) best = v;
        }
        pm = 0xFFFFFFFFu - (unsigned)(best & 0xFFFFFFFFull);
    }
    bool dead = false;
    for (int m2 = 1; m2 < M; ++m2) {
        unsigned int p2 = __shfl(pm, m2);
        if (tid < m2 && p2 == pm) dead = true;   // a later m claims same prior
    }
    if (tid < M && !dead)
        cmb[(size_t)b * P + pm] =
            (unsigned short)((labels[b * M + tid] + 1) | (tid << 8));
    if (tid == 0) {
        loss_l[b] = 0.0;
        pos_ce[b] = 0.0;
        num_pos[b] = 0;
    }
}

// ---------- Kernel C1: pure-stream logsumexp - x[0] ----------
// block = 256 thr handles 64 rows = 20736 B, block base 16B-aligned.
__global__ __launch_bounds__(256) void stream_lse_kernel(
    const float* __restrict__ conf_data,  // [B*P, 81]
    float* __restrict__ loss_rank)        // [B*P] out: lse - x[0]
{
    const int tid = threadIdx.x;
    __shared__ float s[RPB * LDS_PITCH];  // 64*85 dwords = 21760 B

    const size_t gbase = (size_t)blockIdx.x * (RPB * NUM_CLASSES); // dwords
    const float4* src4 = (const float4*)(conf_data + gbase);       // 16B-aligned

    for (int f = tid; f < (RPB * NUM_CLASSES) / 4; f += 256) {
        float4 v = src4[f];
        int d = 4 * f;
#pragma unroll
        for (int j = 0; j < 4; ++j) {
            int dj  = d + j;
            int row = (unsigned)dj / NUM_CLASSES;
            int col = dj - row * NUM_CLASSES;
            s[row * LDS_PITCH + col] = ((const float*)&v)[j];
        }
    }
    __syncthreads();

    const int rq = tid >> 2;        // row 0..63
    const int l  = tid & 3;         // quad lane
    const float* srow = s + rq * LDS_PITCH;
    float a0 = 0.f, a1 = 0.f, a2 = 0.f, a3 = 0.f;
#pragma unroll
    for (int j = 0; j < 20; j += 4) {
        a0 += __expf(srow[l * 20 + j]);
        a1 += __expf(srow[l * 20 + j + 1]);
        a2 += __expf(srow[l * 20 + j + 2]);
        a3 += __expf(srow[l * 20 + j + 3]);
    }
    float sum = (a0 + a1) + (a2 + a3);
    sum += __shfl_xor(sum, 1);
    sum += __shfl_xor(sum, 2);
    if (l == 0) {
        float se = sum + __expf(srow[80]);
        loss_rank[blockIdx.x * RPB + rq] = __logf(se) - srow[0];
    }
}

// ---------- Kernel C2: sparse positive fixup ----------
__global__ __launch_bounds__(256) void fixup_kernel(
    const float* __restrict__ conf_data,
    const float* __restrict__ loc_data,
    const float* __restrict__ priors,
    const float* __restrict__ truths,
    const unsigned short* __restrict__ cmb,
    float*  __restrict__ loss_rank,
    double* __restrict__ loss_l,
    double* __restrict__ pos_ce,
    int*    __restrict__ num_pos)
{
    const int r    = blockIdx.x * 256 + threadIdx.x;   // grid sized exactly
    const int lane = threadIdx.x & 63;
    const int b    = (unsigned)r / P;
    const int p    = r - b * P;

    unsigned cm = cmb[r];
    int conf = cm & 0xFF;
    float ll = 0.f, ce = 0.f;
    int np = 0;
    if (conf > 0) {
        int mt = cm >> 8;
        const float* x = conf_data + (size_t)r * NUM_CLASSES;
        float lr = loss_rank[r];
        ce = lr + x[0] - x[conf];
        loss_rank[r] = 0.f;
        np = 1;
        float4 t  = ((const float4*)truths)[b * M + mt];
        float4 pr = ((const float4*)priors)[p];
        float4 ld = ((const float4*)loc_data)[r];
        float gcx = ((t.x + t.z) * 0.5f - pr.x) / (0.1f * pr.z);
        float gcy = ((t.y + t.w) * 0.5f - pr.y) / (0.1f * pr.w);
        float gw  = logf((t.z - t.x) / pr.z) / 0.2f;
        float gh  = logf((t.w - t.y) / pr.w) / 0.2f;
        ll = sl1f(ld.x - gcx) + sl1f(ld.y - gcy) + sl1f(ld.z - gw) + sl1f(ld.w - gh);
    }

    if (!__any(np)) return;   // negative-only waves skip reduce + atomics

    int b0 = __shfl(b, 0);
    bool uni = __all(b == b0);
    if (uni) {
#pragma unroll
        for (int off = 32; off; off >>= 1) {
            ll += __shfl_xor(ll, off);
            ce += __shfl_xor(ce, off);
            np += __shfl_xor(np, off);
        }
        if (lane == 0 && np > 0) {
            atomicAdd(&loss_l[b0], (double)ll);
            atomicAdd(&pos_ce[b0], (double)ce);
            atomicAdd(&num_pos[b0], np);
        }
    } else if (conf > 0) {
        atomicAdd(&loss_l[b], (double)ll);
        atomicAdd(&pos_ce[b], (double)ce);
        atomicAdd(&num_pos[b], np);
    }
}

// ---------- Kernel D: top-k sum via radix select (parallel bucket scan) ----------
__global__ __launch_bounds__(1024) void topk_kernel(
    const float*  __restrict__ loss_rank, // [B,P] nonneg floats
    const int*    __restrict__ num_pos,   // [B]
    const double* __restrict__ pos_ce,    // [B]
    double*       __restrict__ loss_c)    // [B] out
{
    const int b   = blockIdx.x;
    const int tid = threadIdx.x;
    const int NT  = 1024;
    const int NW  = NT / 64;
    __shared__ unsigned int s_key[P];
    __shared__ unsigned int s_hist[256];
    __shared__ unsigned int s_suf[256];
    __shared__ unsigned int s_wtot[4];
    __shared__ unsigned int s_prefix;
    __shared__ int s_rem;
    __shared__ double s_dl[NW];
    __shared__ int    s_ci[NW];

    const unsigned int* src = (const unsigned int*)(loss_rank + (size_t)b * P);
    for (int p = tid; p < P; p += NT) s_key[p] = src[p];
    int k = num_pos[b] * 3;
    if (k > P - 1) k = P - 1;
    __syncthreads();

    unsigned int prefix = 0;
    if (k > 0) {
        int rem = k;
        for (int byte = 3; byte >= 0; --byte) {
            if (tid < 256) s_hist[tid] = 0;
            __syncthreads();
            unsigned int himask = (byte == 3) ? 0u : (0xFFFFFFFFu << ((byte + 1) * 8));
            for (int p = tid; p < P; p += NT) {
                unsigned int key = s_key[p];
                if ((key & himask) == prefix)
                    atomicAdd(&s_hist[(key >> (byte * 8)) & 255u], 1u);
            }
            __syncthreads();
            // parallel suffix sum over 256 buckets (threads 0..255 = waves 0..3)
            if (tid < 256) {
                unsigned x = s_hist[tid];
#pragma unroll
                for (int off = 1; off < 64; off <<= 1) {
                    unsigned y = __shfl_down(x, off);
                    if ((tid & 63) + off < 64) x += y;
                }
                s_suf[tid] = x;                      // in-wave inclusive suffix
                if ((tid & 63) == 0) s_wtot[tid >> 6] = x;
            }
            __syncthreads();
            if (tid < 256) {
                unsigned above_w = 0;
                int w = tid >> 6;
                for (int w2 = w + 1; w2 < 4; ++w2) above_w += s_wtot[w2];
                unsigned h    = s_hist[tid];
                unsigned incl = s_suf[tid] + above_w;   // keys in buckets >= tid
                unsigned above = incl - h;              // keys in buckets >  tid
                if ((int)above < rem && rem <= (int)incl) {
                    s_prefix = prefix | ((unsigned)tid << (byte * 8));
                    s_rem = rem - (int)above;
                }
            }
            __syncthreads();
            prefix = s_prefix;
            rem    = s_rem;
        }
    }

    double sum_gt = 0.0;
    int    cnt_gt = 0;
    if (k > 0) {
        for (int p = tid; p < P; p += NT) {
            unsigned int key = s_key[p];
            if (key > prefix) { sum_gt += (double)__uint_as_float(key); ++cnt_gt; }
        }
    }
    for (int off = 32; off; off >>= 1) {
        sum_gt += __shfl_xor(sum_gt, off);
        cnt_gt += __shfl_xor(cnt_gt, off);
    }
    const int wid = tid >> 6;
    if ((tid & 63) == 0) { s_dl[wid] = sum_gt; s_ci[wid] = cnt_gt; }
    __syncthreads();
    if (tid == 0) {
        double sg = 0.0; int cg = 0;
        for (int w = 0; w < NW; ++w) { sg += s_dl[w]; cg += s_ci[w]; }
        double tk = 0.0;
        if (k > 0) tk = sg + (double)(k - cg) * (double)__uint_as_float(prefix);
        loss_c[b] = pos_ce[b] + tk;
    }
}

// ---------- Kernel E: final reduction ----------
__global__ void final_kernel(const double* __restrict__ loss_l,
                             const double* __restrict__ loss_c,
                             const int*    __restrict__ num_pos,
                             float* __restrict__ out)
{
    int t = threadIdx.x; // 64 threads
    double ll = loss_l[t];
    double lc = loss_c[t];
    int    n  = num_pos[t];
    for (int off = 32; off; off >>= 1) {
        ll += __shfl_xor(ll, off);
        lc += __shfl_xor(lc, off);
        n  += __shfl_xor(n, off);
    }
    if (t == 0) {
        double N = (double)n;
        out[0] = (float)(ll / N);
        out[1] = (float)(lc / N);
    }
}

extern "C" void kernel_launch(void* const* d_in, const int* in_sizes, int n_in,
                              void* d_out, int out_size, void* d_ws, size_t ws_size,
                              hipStream_t stream)
{
    const float* loc_data  = (const float*)d_in[0];
    const float* conf_data = (const float*)d_in[1];
    const float* priors    = (const float*)d_in[2];
    const float* truths    = (const float*)d_in[3];
    const int*   labels    = (const int*)d_in[4];
    float* out = (float*)d_out;

    char* ws = (char*)d_ws;
    size_t off = 0;
    float* loss_rank = (float*)(ws + off);             off += (size_t)R_TOTAL * 4;
    unsigned short* cmb = (unsigned short*)(ws + off); off += (size_t)R_TOTAL * 2;
    off = (off + 15) & ~(size_t)15;
    unsigned long long* bpk_part = (unsigned long long*)(ws + off);
    off += (size_t)BATCH * NBLK_A * M * 8;
    int*    num_pos = (int*)(ws + off);    off += 64 * sizeof(int);
    double* loss_l  = (double*)(ws + off); off += 64 * sizeof(double);
    double* pos_ce  = (double*)(ws + off); off += 64 * sizeof(double);
    double* loss_c  = (double*)(ws + off); off += 64 * sizeof(double);

    dim3 gA(NBLK_A, BATCH);
    prior_match_kernel<<<gA, 256, 0, stream>>>(priors, truths, labels, cmb, bpk_part);
    force_match_kernel<<<BATCH, 64, 0, stream>>>(bpk_part, labels, cmb,
                                                 loss_l, pos_ce, num_pos);
    stream_lse_kernel<<<R_TOTAL / RPB, 256, 0, stream>>>(conf_data, loss_rank);
    fixup_kernel<<<R_TOTAL / 256, 256, 0, stream>>>(conf_data, loc_data, priors, truths,
                                                    cmb, loss_rank, loss_l, pos_ce, num_pos);
    topk_kernel<<<BATCH, 1024, 0, stream>>>(loss_rank, num_pos, pos_ce, loss_c);
    final_kernel<<<1, 64, 0, stream>>>(loss_l, loss_c, num_pos, out);
}

// Round 7
// 88.333 us; speedup vs baseline: 5.1311x; 1.6237x over previous
//
#include <hip/hip_runtime.h>
#include <math.h>

#define NUM_CLASSES 81
#define BATCH 64
#define P 8732
#define M 24
#define THRESH 0.5f
#define R_TOTAL (BATCH * P)          // 558848
#define RPB 64                       // rows per block in stream kernel
#define PPB_A 1024                   // priors per block in match kernel
#define NBLK_A 9                     // ceil(P / PPB_A)

__device__ __forceinline__ float sl1f(float d) {
    float a = fabsf(d);
    return a < 1.f ? 0.5f * a * a : a - 0.5f;
}

__device__ __forceinline__ unsigned long long packkey(float v, int p) {
    return ((unsigned long long)__float_as_uint(v) << 32)
         | (unsigned long long)(0xFFFFFFFFu - (unsigned)p);
}

// ---------- Kernel A: per-prior match; per-truth best via wave shuffle reduce ----------
// 4 priors per thread, m-outer / j-inner (8 scalar regs of running state, no M-arrays).
__global__ __launch_bounds__(256) void prior_match_kernel(
    const float* __restrict__ priors,   // [P,4] center-size
    const float* __restrict__ truths,   // [B,M,4] corners
    const int*   __restrict__ labels,   // [B,M]
    unsigned short* __restrict__ cmb,   // [B,P] conf | (bti<<8)
    unsigned long long* __restrict__ bpk_part) // [B,NBLK_A,M] per-block partial best
{
    const int b    = blockIdx.y;
    const int tid  = threadIdx.x;
    const int base = blockIdx.x * PPB_A;
    const int wid  = tid >> 6;

    __shared__ float s_truth[M][4];
    __shared__ float s_area[M];
    __shared__ int   s_label[M];
    __shared__ float s_v[4][M];
    __shared__ int   s_ix[4][M];

    if (tid < M * 4) ((float*)s_truth)[tid] = truths[b * M * 4 + tid];
    if (tid < M)     s_label[tid] = labels[b * M + tid];
    __syncthreads();
    if (tid < M)
        s_area[tid] = (s_truth[tid][2] - s_truth[tid][0]) * (s_truth[tid][3] - s_truth[tid][1]);
    __syncthreads();

    float bx0[4], by0[4], bx1[4], by1[4], ab[4];
    bool  val[4];
#pragma unroll
    for (int j = 0; j < 4; ++j) {
        int p = base + tid + j * 256;
        val[j] = (p < P);
        float4 pr = ((const float4*)priors)[val[j] ? p : 0];
        bx0[j] = pr.x - pr.z * 0.5f; by0[j] = pr.y - pr.w * 0.5f;
        bx1[j] = pr.x + pr.z * 0.5f; by1[j] = pr.y + pr.w * 0.5f;
        ab[j]  = (bx1[j] - bx0[j]) * (by1[j] - by0[j]);
    }
    float bestv[4] = {-1.f, -1.f, -1.f, -1.f};
    int   bestm[4] = {0, 0, 0, 0};

    for (int m = 0; m < M; ++m) {
        const float tx0 = s_truth[m][0], ty0 = s_truth[m][1];
        const float tx1 = s_truth[m][2], ty1 = s_truth[m][3];
        const float ta  = s_area[m];
        float vmax = -1.f; int ixm = 0x7FFFFFFF;
#pragma unroll
        for (int j = 0; j < 4; ++j) {
            float lx = fmaxf(tx0, bx0[j]);
            float ly = fmaxf(ty0, by0[j]);
            float rx = fminf(tx1, bx1[j]);
            float ry = fminf(ty1, by1[j]);
            float w = fmaxf(rx - lx, 0.f), h = fmaxf(ry - ly, 0.f);
            float inter = w * h;
            float iou = inter / (ta + ab[j] - inter);
            if (!val[j]) iou = -1.f;
            if (iou > bestv[j]) { bestv[j] = iou; bestm[j] = m; }   // first m wins ties
            if (iou > vmax) { vmax = iou; ixm = base + tid + j * 256; } // smaller p wins
        }
        float v = vmax; int ix = ixm;
#pragma unroll
        for (int off = 32; off; off >>= 1) {
            float vo = __shfl_xor(v, off);
            int   io = __shfl_xor(ix, off);
            if (vo > v || (vo == v && io < ix)) { v = vo; ix = io; }
        }
        if ((tid & 63) == 0) { s_v[wid][m] = v; s_ix[wid][m] = ix; }
    }
    __syncthreads();
    if (tid < M) {
        float v = s_v[0][tid]; int ix = s_ix[0][tid];
#pragma unroll
        for (int w = 1; w < 4; ++w) {
            float vo = s_v[w][tid]; int io = s_ix[w][tid];
            if (vo > v || (vo == v && io < ix)) { v = vo; ix = io; }
        }
        bpk_part[((size_t)b * NBLK_A + blockIdx.x) * M + tid] =
            (v >= 0.f) ? packkey(v, ix) : 0ull;
    }
#pragma unroll
    for (int j = 0; j < 4; ++j) {
        if (val[j]) {
            int p = base + tid + j * 256;
            int conf = (bestv[j] < THRESH) ? 0 : (s_label[bestm[j]] + 1);
            cmb[(size_t)b * P + p] = (unsigned short)(conf | (bestm[j] << 8));
        }
    }
}

// ---------- Kernel B: merge partials, forced matches ----------
__global__ __launch_bounds__(64) void force_match_kernel(
    const unsigned long long* __restrict__ bpk_part,
    const int* __restrict__ labels,
    unsigned short* __restrict__ cmb)
{
    const int b   = blockIdx.x;
    const int tid = threadIdx.x;
    unsigned int pm = 0xFFFFFFFFu;
    if (tid < M) {
        unsigned long long best = 0ull;
        const unsigned long long* part = bpk_part + (size_t)b * NBLK_A * M + tid;
#pragma unroll
        for (int blk = 0; blk < NBLK_A; ++blk) {
            unsigned long long v = part[(size_t)blk * M];
            if (v > best) best = v;
        }
        pm = 0xFFFFFFFFu - (unsigned)(best & 0xFFFFFFFFull);
    }
    bool dead = false;
    for (int m2 = 1; m2 < M; ++m2) {
        unsigned int p2 = __shfl(pm, m2);
        if (tid < m2 && p2 == pm) dead = true;   // a later m claims same prior
    }
    if (tid < M && !dead)
        cmb[(size_t)b * P + pm] =
            (unsigned short)((labels[b * M + tid] + 1) | (tid << 8));
}

// ---------- Kernel C: pure-stream logsumexp - x[0] (raw-layout LDS staging) ----------
// block = 256 thr handles 64 rows = 20736 B, block base 16B-aligned.
__global__ __launch_bounds__(256) void stream_lse_kernel(
    const float* __restrict__ conf_data,  // [B*P, 81]
    float* __restrict__ loss_rank)        // [B*P] out: lse - x[0]
{
    const int tid = threadIdx.x;
    __shared__ float s[RPB * NUM_CLASSES];            // 5184 dwords = 20736 B

    const size_t gbase = (size_t)blockIdx.x * (RPB * NUM_CLASSES);
    const float4* src4 = (const float4*)(conf_data + gbase);  // 16B-aligned
    float4* s4 = (float4*)s;
#pragma unroll
    for (int f = tid; f < (RPB * NUM_CLASSES) / 4; f += 256)
        s4[f] = src4[f];                               // aligned ds_write_b128
    __syncthreads();

    const int rq = tid >> 2;        // row 0..63
    const int l  = tid & 3;         // quad lane
    const float* srow = s + rq * NUM_CLASSES;          // stride 81 (odd): <=2-way banks
    float a0 = 0.f, a1 = 0.f, a2 = 0.f, a3 = 0.f;
#pragma unroll
    for (int j = 0; j < 20; j += 4) {
        a0 += __expf(srow[l * 20 + j]);
        a1 += __expf(srow[l * 20 + j + 1]);
        a2 += __expf(srow[l * 20 + j + 2]);
        a3 += __expf(srow[l * 20 + j + 3]);
    }
    float sum = (a0 + a1) + (a2 + a3);
    sum += __shfl_xor(sum, 1);
    sum += __shfl_xor(sum, 2);
    if (l == 0) {
        float se = sum + __expf(srow[80]);
        loss_rank[blockIdx.x * RPB + rq] = __logf(se) - srow[0];
    }
}

// ---------- Kernel D: fused positive-fixup + top-k radix select (one block/batch) ----------
__global__ __launch_bounds__(1024) void topk_kernel(
    const float* __restrict__ loss_rank,   // [B,P]: lse - x[0]
    const unsigned short* __restrict__ cmb,
    const float* __restrict__ conf_data,
    const float* __restrict__ loc_data,
    const float* __restrict__ priors,
    const float* __restrict__ truths,
    double* __restrict__ loss_l_out,       // [B]
    double* __restrict__ loss_c_out,       // [B]
    int*    __restrict__ num_pos_out)      // [B]
{
    const int b   = blockIdx.x;
    const int tid = threadIdx.x;
    const int NT  = 1024;
    const int NW  = NT / 64;
    const int lane = tid & 63;
    const int wid  = tid >> 6;

    __shared__ unsigned int s_key[P];
    __shared__ unsigned int s_hist[256];
    __shared__ unsigned int s_suf[256];
    __shared__ unsigned int s_wtot[4];
    __shared__ unsigned int s_prefix;
    __shared__ int s_rem;
    __shared__ double s_dl[NW], s_dc[NW];
    __shared__ int    s_in[NW];
    __shared__ int    s_npt;
    __shared__ double s_llt, s_cet;

    // ---- load + positive fixup phase ----
    double ll = 0.0, ce = 0.0;
    int np = 0;
    for (int p = tid; p < P; p += NT) {
        const int r = b * P + p;
        unsigned cm = cmb[r];
        int conf = cm & 0xFF;
        float lr = loss_rank[r];
        unsigned key = __float_as_uint(lr);
        if (conf > 0) {
            key = 0u;                                  // positives ranked 0
            const float* x = conf_data + (size_t)r * NUM_CLASSES;
            ce += (double)(lr + x[0] - x[conf]);       // = lse - x[conf]
            ++np;
            int mt = cm >> 8;
            float4 t  = ((const float4*)truths)[b * M + mt];
            float4 pr = ((const float4*)priors)[p];
            float4 ld = ((const float4*)loc_data)[r];
            float gcx = ((t.x + t.z) * 0.5f - pr.x) / (0.1f * pr.z);
            float gcy = ((t.y + t.w) * 0.5f - pr.y) / (0.1f * pr.w);
            float gw  = logf((t.z - t.x) / pr.z) / 0.2f;
            float gh  = logf((t.w - t.y) / pr.w) / 0.2f;
            ll += (double)(sl1f(ld.x - gcx) + sl1f(ld.y - gcy)
                         + sl1f(ld.z - gw) + sl1f(ld.w - gh));
        }
        s_key[p] = key;
    }
    // block reduce ll, ce, np
#pragma unroll
    for (int off = 32; off; off >>= 1) {
        ll += __shfl_xor(ll, off);
        ce += __shfl_xor(ce, off);
        np += __shfl_xor(np, off);
    }
    if (lane == 0) { s_dl[wid] = ll; s_dc[wid] = ce; s_in[wid] = np; }
    __syncthreads();
    if (tid == 0) {
        double tl = 0.0, tc = 0.0; int tn = 0;
        for (int w = 0; w < NW; ++w) { tl += s_dl[w]; tc += s_dc[w]; tn += s_in[w]; }
        s_llt = tl; s_cet = tc; s_npt = tn;
    }
    __syncthreads();
    const int np_total = s_npt;
    int k = np_total * 3;
    if (k > P - 1) k = P - 1;

    // ---- radix select: k-th largest key ----
    unsigned int prefix = 0;
    if (k > 0) {
        int rem = k;
        for (int byte = 3; byte >= 0; --byte) {
            if (tid < 256) s_hist[tid] = 0;
            __syncthreads();
            if (byte == 3) {
                // wave-aggregated histogram (value distribution concentrates exp byte)
                const int PADP = ((P + NT - 1) / NT) * NT;
                for (int p = tid; p < PADP; p += NT) {
                    bool act = (p < P);
                    unsigned bkt = act ? (s_key[p] >> 24) : 0u;
                    unsigned long long mask = __ballot(act);
                    while (mask) {
                        int leader = __ffsll(mask) - 1;
                        unsigned lb = __shfl(bkt, leader);
                        unsigned long long same = __ballot(act && bkt == lb);
                        if (lane == leader)
                            atomicAdd(&s_hist[lb], (unsigned)__popcll(same));
                        mask &= ~same;
                    }
                }
            } else {
                unsigned int himask = 0xFFFFFFFFu << ((byte + 1) * 8);
                for (int p = tid; p < P; p += NT) {
                    unsigned int key = s_key[p];
                    if ((key & himask) == prefix)
                        atomicAdd(&s_hist[(key >> (byte * 8)) & 255u], 1u);
                }
            }
            __syncthreads();
            // parallel suffix sum over 256 buckets (threads 0..255 = waves 0..3)
            if (tid < 256) {
                unsigned x = s_hist[tid];
#pragma unroll
                for (int off = 1; off < 64; off <<= 1) {
                    unsigned y = __shfl_down(x, off);
                    if ((tid & 63) + off < 64) x += y;
                }
                s_suf[tid] = x;
                if ((tid & 63) == 0) s_wtot[tid >> 6] = x;
            }
            __syncthreads();
            if (tid < 256) {
                unsigned above_w = 0;
                int w = tid >> 6;
                for (int w2 = w + 1; w2 < 4; ++w2) above_w += s_wtot[w2];
                unsigned h     = s_hist[tid];
                unsigned incl  = s_suf[tid] + above_w;   // keys in buckets >= tid
                unsigned above = incl - h;               // keys in buckets >  tid
                if ((int)above < rem && rem <= (int)incl) {
                    s_prefix = prefix | ((unsigned)tid << (byte * 8));
                    s_rem = rem - (int)above;
                }
            }
            __syncthreads();
            prefix = s_prefix;
            rem    = s_rem;
        }
    }

    // ---- sum of values > T, plus (k - cnt) copies of T ----
    double sum_gt = 0.0;
    int    cnt_gt = 0;
    if (k > 0) {
        for (int p = tid; p < P; p += NT) {
            unsigned int key = s_key[p];
            if (key > prefix) { sum_gt += (double)__uint_as_float(key); ++cnt_gt; }
        }
    }
#pragma unroll
    for (int off = 32; off; off >>= 1) {
        sum_gt += __shfl_xor(sum_gt, off);
        cnt_gt += __shfl_xor(cnt_gt, off);
    }
    if (lane == 0) { s_dl[wid] = sum_gt; s_in[wid] = cnt_gt; }
    __syncthreads();
    if (tid == 0) {
        double sg = 0.0; int cg = 0;
        for (int w = 0; w < NW; ++w) { sg += s_dl[w]; cg += s_in[w]; }
        double tk = 0.0;
        if (k > 0) tk = sg + (double)(k - cg) * (double)__uint_as_float(prefix);
        loss_l_out[b]  = s_llt;
        loss_c_out[b]  = s_cet + tk;
        num_pos_out[b] = np_total;
    }
}

// ---------- Kernel E: final reduction ----------
__global__ void final_kernel(const double* __restrict__ loss_l,
                             const double* __restrict__ loss_c,
                             const int*    __restrict__ num_pos,
                             float* __restrict__ out)
{
    int t = threadIdx.x; // 64 threads
    double ll = loss_l[t];
    double lc = loss_c[t];
    int    n  = num_pos[t];
    for (int off = 32; off; off >>= 1) {
        ll += __shfl_xor(ll, off);
        lc += __shfl_xor(lc, off);
        n  += __shfl_xor(n, off);
    }
    if (t == 0) {
        double N = (double)n;
        out[0] = (float)(ll / N);
        out[1] = (float)(lc / N);
    }
}

extern "C" void kernel_launch(void* const* d_in, const int* in_sizes, int n_in,
                              void* d_out, int out_size, void* d_ws, size_t ws_size,
                              hipStream_t stream)
{
    const float* loc_data  = (const float*)d_in[0];
    const float* conf_data = (const float*)d_in[1];
    const float* priors    = (const float*)d_in[2];
    const float* truths    = (const float*)d_in[3];
    const int*   labels    = (const int*)d_in[4];
    float* out = (float*)d_out;

    char* ws = (char*)d_ws;
    size_t off = 0;
    float* loss_rank = (float*)(ws + off);             off += (size_t)R_TOTAL * 4;
    unsigned short* cmb = (unsigned short*)(ws + off); off += (size_t)R_TOTAL * 2;
    off = (off + 15) & ~(size_t)15;
    unsigned long long* bpk_part = (unsigned long long*)(ws + off);
    off += (size_t)BATCH * NBLK_A * M * 8;
    int*    num_pos = (int*)(ws + off);    off += 64 * sizeof(int);
    off = (off + 7) & ~(size_t)7;
    double* loss_l  = (double*)(ws + off); off += 64 * sizeof(double);
    double* loss_c  = (double*)(ws + off); off += 64 * sizeof(double);

    dim3 gA(NBLK_A, BATCH);
    prior_match_kernel<<<gA, 256, 0, stream>>>(priors, truths, labels, cmb, bpk_part);
    force_match_kernel<<<BATCH, 64, 0, stream>>>(bpk_part, labels, cmb);
    stream_lse_kernel<<<R_TOTAL / RPB, 256, 0, stream>>>(conf_data, loss_rank);
    topk_kernel<<<BATCH, 1024, 0, stream>>>(loss_rank, cmb, conf_data, loc_data,
                                            priors, truths, loss_l, loss_c, num_pos);
    final_kernel<<<1, 64, 0, stream>>>(loss_l, loss_c, num_pos, out);
}